// Round 8
// baseline (443.948 us; speedup 1.0000x reference)
//
#include <hip/hip_runtime.h>
#include <hip/hip_bf16.h>

constexpr int B_ = 4;
constexpr int L_ = 2048;
constexpr int D_ = 256;
constexpr int P_ = 32;
constexpr int CL = 32;
constexpr int NC = L_ / CL;  // 64

#define PI_F 3.14159265358979323846f
#define INV_SQRT_P 0.17677669529663687f

typedef __attribute__((ext_vector_type(8))) short short8_t;
typedef __attribute__((ext_vector_type(4))) float floatx4;

static __device__ inline short f2bf(float f) {
  unsigned int u;
  __builtin_memcpy(&u, &f, 4);
  unsigned int r = (u + 0x7fffu + ((u >> 16) & 1u)) >> 16;
  return (short)r;
}
static __device__ inline float bf2f(short s) {
  unsigned int u = ((unsigned int)(unsigned short)s) << 16;
  float f;
  __builtin_memcpy(&f, &u, 4);
  return f;
}

// device-wide barrier: bar[0]=count, bar[1]=generation (agent scope)
static __device__ inline void gbar(unsigned* bar, unsigned nb) {
  __syncthreads();
  if (threadIdx.x == 0) {
    __threadfence();
    unsigned g = __hip_atomic_load(bar + 1, __ATOMIC_ACQUIRE, __HIP_MEMORY_SCOPE_AGENT);
    unsigned a = __hip_atomic_fetch_add(bar, 1u, __ATOMIC_ACQ_REL, __HIP_MEMORY_SCOPE_AGENT);
    if (a + 1 == nb) {
      __hip_atomic_store(bar, 0u, __ATOMIC_RELAXED, __HIP_MEMORY_SCOPE_AGENT);
      __hip_atomic_fetch_add(bar + 1, 1u, __ATOMIC_RELEASE, __HIP_MEMORY_SCOPE_AGENT);
    } else {
      while (__hip_atomic_load(bar + 1, __ATOMIC_ACQUIRE, __HIP_MEMORY_SCOPE_AGENT) == g)
        __builtin_amdgcn_s_sleep(2);
    }
    __threadfence();
  }
  __syncthreads();
}

// ---------------- wprep: weight casts/transposes + x->bf16 + poff + bar=0 --
__global__ void wprep(const float* __restrict__ x, const float* __restrict__ pos,
                      const float* __restrict__ w_val, const float* __restrict__ w_mem1v,
                      const float* __restrict__ w_off, const float* __restrict__ b_off,
                      const float* __restrict__ w_key, const float* __restrict__ w_gate,
                      const float* __restrict__ w_sk1, const float* __restrict__ w_out,
                      const float* __restrict__ w_sk2, const float* __restrict__ w_mem1o,
                      short* __restrict__ WA, short* __restrict__ W1,
                      short* __restrict__ WO, short* __restrict__ W2T,
                      short* __restrict__ W1OT,
                      short* __restrict__ xbf, float* __restrict__ poff,
                      unsigned* __restrict__ bar) {
  int blk = blockIdx.x, tid = threadIdx.x;
  if (blk == 0 && tid < 8) bar[tid] = 0u;
  if (blk < 384) {
    int idx = blk * 256 + tid;
    int n = idx >> 8, k = idx & 255;
    float v;
    if (n < 256) v = w_val[k * 256 + n];
    else if (n < 288) v = w_mem1v[k * 32 + (n - 256)];
    else if (n < 320) v = w_off[k * 32 + (n - 288)];
    else if (n < 352) v = w_key[k * 32 + (n - 320)];
    else if (n == 352) v = w_gate[k];
    else v = 0.f;
    WA[idx] = f2bf(v);
  } else if (blk < 896) {
    int idx = (blk - 384) * 256 + tid;
    int n = idx >> 9, k = idx & 511;
    W1[idx] = f2bf(w_sk1[k * 256 + n]);
  } else if (blk < 1152) {
    int idx = (blk - 896) * 256 + tid;
    int n = idx >> 8, k = idx & 255;
    WO[idx] = f2bf(w_out[k * 256 + n]);
  } else if (blk < 1184) {
    int idx = (blk - 1152) * 256 + tid;
    int p = idx >> 8, k = idx & 255;
    W2T[idx] = f2bf(w_sk2[k * 32 + p]);
  } else if (blk < 1216) {
    int idx = (blk - 1184) * 256 + tid;
    int d = idx >> 5, p = idx & 31;
    W1OT[idx] = f2bf(w_mem1o[p * 256 + d]);
  } else if (blk < 3264) {
    int idx = ((blk - 1216) * 256 + tid) * 4;
    float4 v = *(const float4*)&x[idx];
    short4 o;
    o.x = f2bf(v.x); o.y = f2bf(v.y); o.z = f2bf(v.z); o.w = f2bf(v.w);
    *(short4*)&xbf[idx] = o;
  } else {
    int idx = (blk - 3264) * 256 + tid;
    int l = idx >> 5, p = idx & 31;
    float a = b_off[p];
    for (int j = 0; j < 32; ++j) a += pos[l * 32 + j] * w_off[(256 + j) * 32 + p];
    poff[idx] = a;
  }
}

// ---------------- generic bf16 MFMA GEMM, 64x64 tile -----------------------
template <int KTILES, int NBLK, int MODE>
__global__ __launch_bounds__(256) void gemm_k(const short* __restrict__ A0,
                                              const short* __restrict__ A1,
                                              const short* __restrict__ W,
                                              const float* __restrict__ bias,
                                              const float* __restrict__ xres,
                                              float* __restrict__ outf,
                                              short* __restrict__ outb) {
  __shared__ short As[64][136];
  __shared__ short Bs[64][136];
  int tid = threadIdx.x;
  int mg = blockIdx.x / NBLK, ng = blockIdx.x % NBLK;
  int tok0 = mg * 64, n0 = ng * 64;
  int lane = tid & 63, w = tid >> 6;
  int mw = (w & 1) * 32, nw = (w >> 1) * 32;
  floatx4 acc[2][2] = {{{0.f, 0.f, 0.f, 0.f}, {0.f, 0.f, 0.f, 0.f}},
                       {{0.f, 0.f, 0.f, 0.f}, {0.f, 0.f, 0.f, 0.f}}};
  int r2 = tid >> 4, c8 = tid & 15;
  int ml = lane & 15, kq = (lane >> 4) * 8;
  const int K = KTILES * 128;

  for (int kt = 0; kt < KTILES; ++kt) {
    const short* Asrc;
    int cb;
    if (KTILES == 4) {
      Asrc = (kt < 2) ? A0 : A1;
      cb = (kt & 1) * 128;
    } else {
      Asrc = A0;
      cb = kt * 128;
    }
#pragma unroll
    for (int pass = 0; pass < 4; ++pass) {
      int row = pass * 16 + r2;
      *(short8_t*)&As[row][c8 * 8] =
          *(const short8_t*)&Asrc[(tok0 + row) * 256 + cb + c8 * 8];
      *(short8_t*)&Bs[row][c8 * 8] =
          *(const short8_t*)&W[(n0 + row) * K + kt * 128 + c8 * 8];
    }
    __syncthreads();
#pragma unroll
    for (int s = 0; s < 4; ++s) {
      short8_t a0 = *(short8_t*)&As[mw + ml][s * 32 + kq];
      short8_t a1 = *(short8_t*)&As[mw + 16 + ml][s * 32 + kq];
      short8_t b0 = *(short8_t*)&Bs[nw + ml][s * 32 + kq];
      short8_t b1 = *(short8_t*)&Bs[nw + 16 + ml][s * 32 + kq];
      acc[0][0] = __builtin_amdgcn_mfma_f32_16x16x32_bf16(a0, b0, acc[0][0], 0, 0, 0);
      acc[0][1] = __builtin_amdgcn_mfma_f32_16x16x32_bf16(a0, b1, acc[0][1], 0, 0, 0);
      acc[1][0] = __builtin_amdgcn_mfma_f32_16x16x32_bf16(a1, b0, acc[1][0], 0, 0, 0);
      acc[1][1] = __builtin_amdgcn_mfma_f32_16x16x32_bf16(a1, b1, acc[1][1], 0, 0, 0);
    }
    __syncthreads();
  }
  int col = lane & 15, rq = (lane >> 4) * 4;
#pragma unroll
  for (int nt = 0; nt < 2; ++nt) {
    int n = n0 + nw + nt * 16 + col;
    float bv = (MODE == 0) ? 0.f : bias[n];
#pragma unroll
    for (int mt = 0; mt < 2; ++mt) {
#pragma unroll
      for (int rg = 0; rg < 4; ++rg) {
        int tok = tok0 + mw + mt * 16 + rq + rg;
        float v = acc[mt][nt][rg] + bv;
        if (MODE == 0) {
          outb[tok * 384 + n] = f2bf(v);
        } else if (MODE == 1) {
          float g = 0.5f * v * (1.f + erff(v * 0.70710678118654752f));
          outb[tok * 256 + n] = f2bf(g);
        } else {
          outf[tok * 256 + n] = xres[tok * 256 + n] + v;
        }
      }
    }
  }
}

// ---------------- Kernel A3SC: phasor prep + all scans + ctx (fused) -------
// grid 516. Phase1 (blk<512): A3 over 16 tokens. Phase2: m1/sg scans + ctx
// chunk sums. Phase3 (blk in [260,516)): ctx local scan -> ctxbf.
__global__ __launch_bounds__(256, 4) void kernelA3SC(
    const short* __restrict__ Ybf, const float* __restrict__ pos,
    const float* __restrict__ poff, const float* __restrict__ b_mem1v,
    const float* __restrict__ b_key, const float* __restrict__ b_gate,
    const float* __restrict__ b_val,
    float* __restrict__ m1cT, float* __restrict__ m1sT,
    float* __restrict__ qc, float* __restrict__ qs,
    short* __restrict__ K2bf, short* __restrict__ gvT,
    float* __restrict__ sg, const float* __restrict__ x,
    float* __restrict__ ctxsum, short* __restrict__ ctxbf,
    unsigned* __restrict__ bar) {
  __shared__ float gsh[16];
  __shared__ float wsum[4];
  int blk = blockIdx.x, tid = threadIdx.x;
  // ---- Phase 1: A3 (16 tokens/block) ----
  if (blk < 512) {
    int tok0 = blk * 16;
#pragma unroll
    for (int h = 0; h < 2; ++h) {
      int t = h * 8 + (tid >> 5), p = tid & 31;
      int tok = tok0 + t, l = tok & (L_ - 1);
      int b = tok >> 11;
      float gate = 1.f / (1.f + expf(-(bf2f(Ybf[tok * 384 + 352]) + b_gate[0])));
      if (p == 0) {
        sg[tok] = gate;
        gsh[t] = gate;
      }
      float v1 = bf2f(Ybf[tok * 384 + 256 + p]) + b_mem1v[p];
      float ph = pos[l * 32 + p];
      float pc = cosf(ph), ps = sinf(ph);
      int idxT = (b * 32 + p) * L_ + l;
      m1cT[idxT] = pc * v1;
      m1sT[idxT] = ps * v1;
      float off = tanhf(bf2f(Ybf[tok * 384 + 288 + p]) + poff[l * 32 + p]) * PI_F;
      float oc = cosf(off), os = sinf(off);
      int idx = tok * 32 + p;
      qc[idx] = pc * oc - ps * os;
      qs[idx] = ps * oc + pc * os;
      float kp = tanhf(bf2f(Ybf[tok * 384 + 320 + p]) + b_key[p]) * PI_F;
      K2bf[tok * 64 + p] = f2bf(cosf(kp));
      K2bf[tok * 64 + 32 + p] = f2bf(sinf(kp));
    }
    __syncthreads();
    {
      int l0 = tok0 & (L_ - 1);
      int bc = (tok0 >> 11) * NC + (l0 >> 5);
      int tl0 = l0 & 31;  // 0 or 16
      short sv[16];
#pragma unroll
      for (int tt = 0; tt < 16; ++tt)
        sv[tt] = f2bf((bf2f(Ybf[(tok0 + tt) * 384 + tid]) + b_val[tid]) * gsh[tt]);
      int gb = (bc * 256 + tid) * 32 + tl0;
      *(short8_t*)&gvT[gb] = *(short8_t*)&sv[0];
      *(short8_t*)&gvT[gb + 8] = *(short8_t*)&sv[8];
    }
  }
  gbar(bar + 0, gridDim.x);
  // ---- Phase 2: scans + ctx chunk sums ----
  if (blk >= 260) {
    int c2 = blk - 260;
    int b = c2 >> 6, ch = c2 & 63;
    int xb = (b * L_ + ch * 32) * 256 + tid;
    float s = 0.f;
#pragma unroll 8
    for (int i = 0; i < 32; ++i) s += x[xb + i * 256];
    ctxsum[c2 * 256 + tid] = s;
  } else {
    int lane = tid & 63, wid = tid >> 6;
    float carry = 0.f;
    float* arr;
    int base;
    if (blk < 256) {
      arr = (blk < 128) ? m1cT : m1sT;
      base = (blk & 127) * L_;
    } else {
      arr = sg;
      base = (blk - 256) * L_;
    }
    for (int t0 = 0; t0 < L_; t0 += 256) {
      int l = t0 + tid;
      float v = arr[base + l];
#pragma unroll
      for (int off = 1; off < 64; off <<= 1) {
        float n = __shfl_up(v, off, 64);
        if (lane >= off) v += n;
      }
      if (lane == 63) wsum[wid] = v;
      __syncthreads();
      float add = carry;
      for (int w = 0; w < wid; ++w) add += wsum[w];
      arr[base + l] = v + add;
      carry += wsum[0] + wsum[1] + wsum[2] + wsum[3];
      __syncthreads();
    }
  }
  gbar(bar + 2, gridDim.x);
  // ---- Phase 3: ctx local scan -> ctxbf ----
  if (blk >= 260) {
    int c2 = blk - 260;
    int b = c2 >> 6, ch = c2 & 63;
    float run = 0.f;
    int sb = b * 64 * 256 + tid;
    for (int c = 0; c < ch; ++c) run += ctxsum[sb + c * 256];
    int xb = (b * L_ + ch * 32) * 256 + tid;
#pragma unroll 8
    for (int i = 0; i < 32; ++i) {
      run += x[xb + i * 256];
      int l = ch * 32 + i;
      ctxbf[xb + i * 256] = f2bf(run / (float)(l + 1));
    }
  }
}

// ---------------- Kernel KV: CD + E + FG fused (grid 256, 2 barriers) ------
__global__ __launch_bounds__(256) void kernelKV(
    const short* __restrict__ hs, const short* __restrict__ W2T,
    const float* __restrict__ b_sk2, const short* __restrict__ gvT,
    short* __restrict__ SPbf, short* __restrict__ UT,
    const short* __restrict__ K2bf, const float* __restrict__ sgc,
    const float* __restrict__ m1cT, const float* __restrict__ m1sT,
    const float* __restrict__ qc, const float* __restrict__ qs,
    const short* __restrict__ W1OT, const float* __restrict__ b_mem1o,
    const float* __restrict__ ln_g, const float* __restrict__ ln_b,
    short* __restrict__ cbn, unsigned* __restrict__ bar) {
  __shared__ __align__(16) char shm[38912];
  int blk = blockIdx.x, tid = threadIdx.x;
  int lane = tid & 63, w = tid >> 6;
  int ml = lane & 15, quad = lane >> 4, kq = quad * 8;
  // ---- Phase CD (blk < 128): sk2 phases + chunk U sums ----
  if (blk < 128) {
    short* SPL = (short*)shm;  // [2][64][40]
    int tok0 = blk * 64;
    int m0 = w * 16;
    floatx4 pacc[2] = {};
#pragma unroll
    for (int s = 0; s < 8; ++s) {
      short8_t a = *(const short8_t*)&hs[(tok0 + m0 + ml) * 256 + s * 32 + kq];
      short8_t b0 = *(const short8_t*)&W2T[ml * 256 + s * 32 + kq];
      short8_t b1 = *(const short8_t*)&W2T[(16 + ml) * 256 + s * 32 + kq];
      pacc[0] = __builtin_amdgcn_mfma_f32_16x16x32_bf16(a, b0, pacc[0], 0, 0, 0);
      pacc[1] = __builtin_amdgcn_mfma_f32_16x16x32_bf16(a, b1, pacc[1], 0, 0, 0);
    }
    int cl = w >> 1;
#pragma unroll
    for (int nt = 0; nt < 2; ++nt) {
      int p = nt * 16 + ml;
      float bs = b_sk2[p];
#pragma unroll
      for (int r = 0; r < 4; ++r) {
        int tok = tok0 + m0 + quad * 4 + r;
        float sp = tanhf(pacc[nt][r] + bs) * PI_F;
        short c = f2bf(cosf(sp)), s = f2bf(sinf(sp));
        int tl = (w & 1) * 16 + quad * 4 + r;
        SPL[(cl * 64 + p) * 40 + tl] = c;
        SPL[(cl * 64 + 32 + p) * 40 + tl] = s;
        SPbf[tok * 64 + p] = c;
        SPbf[tok * 64 + 32 + p] = s;
      }
    }
    __syncthreads();
    int c2 = w & 1, dbase = (w >> 1) * 128;
    int bc = blk * 2 + c2;
    short8_t a[4];
#pragma unroll
    for (int mt = 0; mt < 4; ++mt)
      a[mt] = *(short8_t*)&SPL[(c2 * 64 + mt * 16 + ml) * 40 + kq];
#pragma unroll
    for (int dp = 0; dp < 2; ++dp) {
      floatx4 acc[4][4] = {};
#pragma unroll
      for (int nt = 0; nt < 4; ++nt) {
        short8_t b = *(const short8_t*)&gvT[(bc * 256 + dbase + dp * 64 + nt * 16 + ml) * 32 + kq];
#pragma unroll
        for (int mt = 0; mt < 4; ++mt)
          acc[mt][nt] = __builtin_amdgcn_mfma_f32_16x16x32_bf16(a[mt], b, acc[mt][nt], 0, 0, 0);
      }
#pragma unroll
      for (int mt = 0; mt < 4; ++mt)
#pragma unroll
        for (int nt = 0; nt < 4; ++nt)
#pragma unroll
          for (int r = 0; r < 4; ++r) {
            int q = mt * 16 + quad * 4 + r;
            int d = dbase + dp * 64 + nt * 16 + ml;
            UT[(bc * 256 + d) * 64 + q] = f2bf(acc[mt][nt][r]);
          }
    }
  }
  gbar(bar + 4, gridDim.x);
  // ---- Phase E: exclusive chunk prefix (bf16, all 256 blocks) ----
  {
    int gt = blk * 256 + tid;
    int q = gt & 63;
    int d = (gt >> 6) & 255;
    int b = gt >> 14;
    int base = ((b * NC) * 256 + d) * 64 + q;
    const int cs = 256 * 64;
    float run = 0.f;
    for (int c0 = 0; c0 < NC; c0 += 8) {
      short v[8];
#pragma unroll
      for (int j = 0; j < 8; ++j) v[j] = UT[base + (c0 + j) * cs];
#pragma unroll
      for (int j = 0; j < 8; ++j) {
        UT[base + (c0 + j) * cs] = f2bf(run);
        run += bf2f(v[j]);
      }
    }
  }
  gbar(bar + 6, gridDim.x);
  // ---- Phase FG: retrieval + pos_out + LN -> cbn ----
  {
    short* SL = (short*)shm;                    // [32][40]
    short* PR = SL + 32 * 40;                   // [32][40]
    float* CMB = (float*)(shm + 5120);          // [32][260]
    float* scl = (float*)(shm + 5120 + 33280);  // [32]
    float* mu_s = scl + 32;
    float* rs_s = scl + 64;
    int bc = blk;
    int lbase = bc * CL;
    int bb = bc >> 6, lloc = (bc & 63) * 32;
    if (tid < 32) scl[tid] = rsqrtf(fmaxf(sgc[lbase + tid], 1.f)) * INV_SQRT_P;
    for (int it = 0; it < 4; ++it) {
      int i = it * 256 + tid;
      int p = i >> 5, t = i & 31;
      int gT = (bb * 32 + p) * L_ + lloc + t;
      int g = (lbase + t) * 32 + p;
      PR[t * 40 + p] = f2bf((m1cT[gT] * qc[g] + m1sT[gT] * qs[g]) * INV_SQRT_P);
    }
    floatx4 acc[2][4] = {};
    short8_t ka0 = *(const short8_t*)&K2bf[(lbase + ml) * 64 + kq];
    short8_t ka1 = *(const short8_t*)&K2bf[(lbase + 16 + ml) * 64 + kq];
    short8_t kb0 = *(const short8_t*)&K2bf[(lbase + ml) * 64 + 32 + kq];
    short8_t kb1 = *(const short8_t*)&K2bf[(lbase + 16 + ml) * 64 + 32 + kq];
#pragma unroll
    for (int nt = 0; nt < 4; ++nt) {
      short8_t b = *(const short8_t*)&UT[(bc * 256 + w * 64 + nt * 16 + ml) * 64 + kq];
      acc[0][nt] = __builtin_amdgcn_mfma_f32_16x16x32_bf16(ka0, b, acc[0][nt], 0, 0, 0);
      acc[1][nt] = __builtin_amdgcn_mfma_f32_16x16x32_bf16(ka1, b, acc[1][nt], 0, 0, 0);
    }
    if (w == 0) {
      floatx4 sacc[2][2] = {};
#pragma unroll
      for (int ks2 = 0; ks2 < 2; ++ks2) {
        short8_t a0 = (ks2 == 0) ? ka0 : kb0;
        short8_t a1 = (ks2 == 0) ? ka1 : kb1;
        short8_t b0 = *(const short8_t*)&SPbf[(lbase + ml) * 64 + ks2 * 32 + kq];
        short8_t b1 = *(const short8_t*)&SPbf[(lbase + 16 + ml) * 64 + ks2 * 32 + kq];
        sacc[0][0] = __builtin_amdgcn_mfma_f32_16x16x32_bf16(a0, b0, sacc[0][0], 0, 0, 0);
        sacc[0][1] = __builtin_amdgcn_mfma_f32_16x16x32_bf16(a0, b1, sacc[0][1], 0, 0, 0);
        sacc[1][0] = __builtin_amdgcn_mfma_f32_16x16x32_bf16(a1, b0, sacc[1][0], 0, 0, 0);
        sacc[1][1] = __builtin_amdgcn_mfma_f32_16x16x32_bf16(a1, b1, sacc[1][1], 0, 0, 0);
      }
#pragma unroll
      for (int mt = 0; mt < 2; ++mt)
#pragma unroll
        for (int nt = 0; nt < 2; ++nt)
#pragma unroll
          for (int r = 0; r < 4; ++r) {
            int trow = mt * 16 + quad * 4 + r;
            int scol = nt * 16 + ml;
            float v = (scol <= trow) ? sacc[mt][nt][r] : 0.f;
            SL[trow * 40 + scol] = f2bf(v);
          }
    }
    __syncthreads();
#pragma unroll
    for (int nt = 0; nt < 4; ++nt) {
      short8_t b = *(const short8_t*)&UT[(bc * 256 + w * 64 + nt * 16 + ml) * 64 + 32 + kq];
      acc[0][nt] = __builtin_amdgcn_mfma_f32_16x16x32_bf16(kb0, b, acc[0][nt], 0, 0, 0);
      acc[1][nt] = __builtin_amdgcn_mfma_f32_16x16x32_bf16(kb1, b, acc[1][nt], 0, 0, 0);
    }
    {
      short8_t a0 = *(short8_t*)&SL[ml * 40 + kq];
      short8_t a1 = *(short8_t*)&SL[(16 + ml) * 40 + kq];
#pragma unroll
      for (int nt = 0; nt < 4; ++nt) {
        short8_t b = *(const short8_t*)&gvT[(bc * 256 + w * 64 + nt * 16 + ml) * 32 + kq];
        acc[0][nt] = __builtin_amdgcn_mfma_f32_16x16x32_bf16(a0, b, acc[0][nt], 0, 0, 0);
        acc[1][nt] = __builtin_amdgcn_mfma_f32_16x16x32_bf16(a1, b, acc[1][nt], 0, 0, 0);
      }
    }
    floatx4 macc[2][4] = {};
    {
      short8_t a0 = *(short8_t*)&PR[ml * 40 + kq];
      short8_t a1 = *(short8_t*)&PR[(16 + ml) * 40 + kq];
#pragma unroll
      for (int nt = 0; nt < 4; ++nt) {
        short8_t b = *(const short8_t*)&W1OT[(w * 64 + nt * 16 + ml) * 32 + kq];
        macc[0][nt] = __builtin_amdgcn_mfma_f32_16x16x32_bf16(a0, b, macc[0][nt], 0, 0, 0);
        macc[1][nt] = __builtin_amdgcn_mfma_f32_16x16x32_bf16(a1, b, macc[1][nt], 0, 0, 0);
      }
    }
#pragma unroll
    for (int mt = 0; mt < 2; ++mt)
#pragma unroll
      for (int nt = 0; nt < 4; ++nt) {
        int d = w * 64 + nt * 16 + ml;
        float bm = b_mem1o[d];
#pragma unroll
        for (int r = 0; r < 4; ++r) {
          int t = mt * 16 + quad * 4 + r;
          CMB[t * 260 + d] = acc[mt][nt][r] * scl[t] + macc[mt][nt][r] + bm;
        }
      }
    __syncthreads();
    {
      int t = tid >> 3, g = tid & 7;
      float s = 0.f, s2 = 0.f;
#pragma unroll
      for (int j = 0; j < 32; ++j) {
        float v = CMB[t * 260 + g + j * 8];
        s += v;
        s2 += v * v;
      }
#pragma unroll
      for (int m = 1; m < 8; m <<= 1) {
        s += __shfl_xor(s, m, 64);
        s2 += __shfl_xor(s2, m, 64);
      }
      if (g == 0) {
        float mu = s / (float)D_;
        float var = s2 / (float)D_ - mu * mu;
        mu_s[t] = mu;
        rs_s[t] = rsqrtf(var + 1e-5f);
      }
    }
    __syncthreads();
    {
      float lg = ln_g[tid], lb = ln_b[tid];
#pragma unroll
      for (int t = 0; t < 32; ++t)
        cbn[(lbase + t) * 256 + tid] =
            f2bf((CMB[t * 260 + tid] - mu_s[t]) * rs_s[t] * lg + lb);
    }
  }
}

extern "C" void kernel_launch(void* const* d_in, const int* in_sizes, int n_in,
                              void* d_out, int out_size, void* d_ws, size_t ws_size,
                              hipStream_t stream) {
  const float* x = (const float*)d_in[0];
  const float* pos = (const float*)d_in[1];
  const float* w_mem1v = (const float*)d_in[2];
  const float* b_mem1v = (const float*)d_in[3];
  const float* w_mem1o = (const float*)d_in[4];
  const float* b_mem1o = (const float*)d_in[5];
  const float* w_off = (const float*)d_in[6];
  const float* b_off = (const float*)d_in[7];
  const float* w_key = (const float*)d_in[8];
  const float* b_key = (const float*)d_in[9];
  const float* w_val = (const float*)d_in[10];
  const float* b_val = (const float*)d_in[11];
  const float* w_sk1 = (const float*)d_in[12];
  const float* b_sk1 = (const float*)d_in[13];
  const float* w_sk2 = (const float*)d_in[14];
  const float* b_sk2 = (const float*)d_in[15];
  const float* w_gate = (const float*)d_in[16];
  const float* b_gate = (const float*)d_in[17];
  const float* ln_g = (const float*)d_in[18];
  const float* ln_b = (const float*)d_in[19];
  const float* w_out = (const float*)d_in[20];
  const float* b_out = (const float*)d_in[21];
  float* out = (float*)d_out;
  float* ws = (float*)d_ws;

  const int BLP = B_ * L_ * P_;  // 262144
  const int BLD = B_ * L_ * D_;  // 2097152
  float* m1cT = ws;
  float* m1sT = m1cT + BLP;
  float* qc = m1sT + BLP;
  float* qs = qc + BLP;
  float* sg = qs + BLP;
  float* poff = sg + B_ * L_;
  float* ctxsum = poff + L_ * P_;
  short* Ybf = (short*)(ctxsum + B_ * 64 * 256);
  short* UT = Ybf;  // aliases Ybf (dead after A3SC)
  short* xbf = UT + (size_t)B_ * NC * 256 * 64;
  short* cbn = xbf;  // aliases xbf (dead after gemm1)
  short* ctxbf = xbf + BLD;
  short* hs = ctxbf + BLD;
  short* gvT = hs + BLD;
  short* K2bf = gvT + BLD;
  short* SPbf = K2bf + B_ * L_ * 64;
  short* WA = SPbf + B_ * L_ * 64;
  short* W1 = WA + 384 * 256;
  short* WO = W1 + 256 * 512;
  short* W2T = WO + 256 * 256;
  short* W1OT = W2T + 32 * 256;
  unsigned* bar = (unsigned*)(W1OT + 256 * 32);

  wprep<<<3520, 256, 0, stream>>>(x, pos, w_val, w_mem1v, w_off, b_off, w_key, w_gate,
                                  w_sk1, w_out, w_sk2, w_mem1o, WA, W1, WO, W2T, W1OT,
                                  xbf, poff, bar);
  gemm_k<2, 6, 0><<<128 * 6, 256, 0, stream>>>(xbf, nullptr, WA, nullptr, nullptr, nullptr, Ybf);
  kernelA3SC<<<516, 256, 0, stream>>>(Ybf, pos, poff, b_mem1v, b_key, b_gate, b_val,
                                      m1cT, m1sT, qc, qs, K2bf, gvT, sg, x, ctxsum,
                                      ctxbf, bar);
  gemm_k<4, 4, 1><<<128 * 4, 256, 0, stream>>>(xbf, ctxbf, W1, b_sk1, nullptr, nullptr, hs);
  kernelKV<<<256, 256, 0, stream>>>(hs, W2T, b_sk2, gvT, SPbf, UT, K2bf, sg,
                                    m1cT, m1sT, qc, qs, W1OT, b_mem1o, ln_g, ln_b,
                                    cbn, bar);
  gemm_k<2, 4, 2><<<128 * 4, 256, 0, stream>>>(cbn, nullptr, WO, b_out, x, out, nullptr);
}

// Round 9
// 361.821 us; speedup vs baseline: 1.2270x; 1.2270x over previous
//
#include <hip/hip_runtime.h>
#include <hip/hip_bf16.h>

constexpr int B_ = 4;
constexpr int L_ = 2048;
constexpr int D_ = 256;
constexpr int P_ = 32;
constexpr int CL = 32;
constexpr int NC = L_ / CL;  // 64

#define PI_F 3.14159265358979323846f
#define INV_SQRT_P 0.17677669529663687f

typedef __attribute__((ext_vector_type(8))) short short8_t;
typedef __attribute__((ext_vector_type(4))) float floatx4;

static __device__ inline short f2bf(float f) {
  unsigned int u;
  __builtin_memcpy(&u, &f, 4);
  unsigned int r = (u + 0x7fffu + ((u >> 16) & 1u)) >> 16;
  return (short)r;
}
static __device__ inline float bf2f(short s) {
  unsigned int u = ((unsigned int)(unsigned short)s) << 16;
  float f;
  __builtin_memcpy(&f, &u, 4);
  return f;
}

// flag-array device barrier: one release store per block (parallel commits),
// distributed relaxed polling. No single-line RMW serialization.
static __device__ inline void gbarf(unsigned* flags, unsigned nb, unsigned gen) {
  __syncthreads();
  if (threadIdx.x == 0) {
    __threadfence();
    __hip_atomic_store(&flags[blockIdx.x], gen, __ATOMIC_RELEASE,
                       __HIP_MEMORY_SCOPE_AGENT);
  }
  for (unsigned i = threadIdx.x; i < nb; i += 256) {
    while (__hip_atomic_load(&flags[i], __ATOMIC_RELAXED,
                             __HIP_MEMORY_SCOPE_AGENT) < gen)
      __builtin_amdgcn_s_sleep(1);
  }
  __threadfence();
  __syncthreads();
}

// ---------------- wprep: weight casts/transposes + x->bf16 + poff + flags=0
__global__ void wprep(const float* __restrict__ x, const float* __restrict__ pos,
                      const float* __restrict__ w_val, const float* __restrict__ w_mem1v,
                      const float* __restrict__ w_off, const float* __restrict__ b_off,
                      const float* __restrict__ w_key, const float* __restrict__ w_gate,
                      const float* __restrict__ w_sk1, const float* __restrict__ w_out,
                      const float* __restrict__ w_sk2, const float* __restrict__ w_mem1o,
                      short* __restrict__ WA, short* __restrict__ W1,
                      short* __restrict__ WO, short* __restrict__ W2T,
                      short* __restrict__ W1OT,
                      short* __restrict__ xbf, float* __restrict__ poff,
                      unsigned* __restrict__ bar) {
  int blk = blockIdx.x, tid = threadIdx.x;
  if (blk < 4) bar[blk * 256 + tid] = 0u;
  if (blk < 384) {
    int idx = blk * 256 + tid;
    int n = idx >> 8, k = idx & 255;
    float v;
    if (n < 256) v = w_val[k * 256 + n];
    else if (n < 288) v = w_mem1v[k * 32 + (n - 256)];
    else if (n < 320) v = w_off[k * 32 + (n - 288)];
    else if (n < 352) v = w_key[k * 32 + (n - 320)];
    else if (n == 352) v = w_gate[k];
    else v = 0.f;
    WA[idx] = f2bf(v);
  } else if (blk < 896) {
    int idx = (blk - 384) * 256 + tid;
    int n = idx >> 9, k = idx & 511;
    W1[idx] = f2bf(w_sk1[k * 256 + n]);
  } else if (blk < 1152) {
    int idx = (blk - 896) * 256 + tid;
    int n = idx >> 8, k = idx & 255;
    WO[idx] = f2bf(w_out[k * 256 + n]);
  } else if (blk < 1184) {
    int idx = (blk - 1152) * 256 + tid;
    int p = idx >> 8, k = idx & 255;
    W2T[idx] = f2bf(w_sk2[k * 32 + p]);
  } else if (blk < 1216) {
    int idx = (blk - 1184) * 256 + tid;
    int d = idx >> 5, p = idx & 31;
    W1OT[idx] = f2bf(w_mem1o[p * 256 + d]);
  } else if (blk < 3264) {
    int idx = ((blk - 1216) * 256 + tid) * 4;
    float4 v = *(const float4*)&x[idx];
    short4 o;
    o.x = f2bf(v.x); o.y = f2bf(v.y); o.z = f2bf(v.z); o.w = f2bf(v.w);
    *(short4*)&xbf[idx] = o;
  } else {
    int idx = (blk - 3264) * 256 + tid;
    int l = idx >> 5, p = idx & 31;
    float a = b_off[p];
    for (int j = 0; j < 32; ++j) a += pos[l * 32 + j] * w_off[(256 + j) * 32 + p];
    poff[idx] = a;
  }
}

// ---------------- generic bf16 MFMA GEMM, 64x64 tile -----------------------
template <int KTILES, int NBLK, int MODE>
__global__ __launch_bounds__(256) void gemm_k(const short* __restrict__ A0,
                                              const short* __restrict__ A1,
                                              const short* __restrict__ W,
                                              const float* __restrict__ bias,
                                              const float* __restrict__ xres,
                                              float* __restrict__ outf,
                                              short* __restrict__ outb) {
  __shared__ short As[64][136];
  __shared__ short Bs[64][136];
  int tid = threadIdx.x;
  int mg = blockIdx.x / NBLK, ng = blockIdx.x % NBLK;
  int tok0 = mg * 64, n0 = ng * 64;
  int lane = tid & 63, w = tid >> 6;
  int mw = (w & 1) * 32, nw = (w >> 1) * 32;
  floatx4 acc[2][2] = {{{0.f, 0.f, 0.f, 0.f}, {0.f, 0.f, 0.f, 0.f}},
                       {{0.f, 0.f, 0.f, 0.f}, {0.f, 0.f, 0.f, 0.f}}};
  int r2 = tid >> 4, c8 = tid & 15;
  int ml = lane & 15, kq = (lane >> 4) * 8;
  const int K = KTILES * 128;

  for (int kt = 0; kt < KTILES; ++kt) {
    const short* Asrc;
    int cb;
    if (KTILES == 4) {
      Asrc = (kt < 2) ? A0 : A1;
      cb = (kt & 1) * 128;
    } else {
      Asrc = A0;
      cb = kt * 128;
    }
#pragma unroll
    for (int pass = 0; pass < 4; ++pass) {
      int row = pass * 16 + r2;
      *(short8_t*)&As[row][c8 * 8] =
          *(const short8_t*)&Asrc[(tok0 + row) * 256 + cb + c8 * 8];
      *(short8_t*)&Bs[row][c8 * 8] =
          *(const short8_t*)&W[(n0 + row) * K + kt * 128 + c8 * 8];
    }
    __syncthreads();
#pragma unroll
    for (int s = 0; s < 4; ++s) {
      short8_t a0 = *(short8_t*)&As[mw + ml][s * 32 + kq];
      short8_t a1 = *(short8_t*)&As[mw + 16 + ml][s * 32 + kq];
      short8_t b0 = *(short8_t*)&Bs[nw + ml][s * 32 + kq];
      short8_t b1 = *(short8_t*)&Bs[nw + 16 + ml][s * 32 + kq];
      acc[0][0] = __builtin_amdgcn_mfma_f32_16x16x32_bf16(a0, b0, acc[0][0], 0, 0, 0);
      acc[0][1] = __builtin_amdgcn_mfma_f32_16x16x32_bf16(a0, b1, acc[0][1], 0, 0, 0);
      acc[1][0] = __builtin_amdgcn_mfma_f32_16x16x32_bf16(a1, b0, acc[1][0], 0, 0, 0);
      acc[1][1] = __builtin_amdgcn_mfma_f32_16x16x32_bf16(a1, b1, acc[1][1], 0, 0, 0);
    }
    __syncthreads();
  }
  int col = lane & 15, rq = (lane >> 4) * 4;
#pragma unroll
  for (int nt = 0; nt < 2; ++nt) {
    int n = n0 + nw + nt * 16 + col;
    float bv = (MODE == 0) ? 0.f : bias[n];
#pragma unroll
    for (int mt = 0; mt < 2; ++mt) {
#pragma unroll
      for (int rg = 0; rg < 4; ++rg) {
        int tok = tok0 + mw + mt * 16 + rq + rg;
        float v = acc[mt][nt][rg] + bv;
        if (MODE == 0) {
          outb[tok * 384 + n] = f2bf(v);
        } else if (MODE == 1) {
          float g = 0.5f * v * (1.f + erff(v * 0.70710678118654752f));
          outb[tok * 256 + n] = f2bf(g);
        } else {
          outf[tok * 256 + n] = xres[tok * 256 + n] + v;
        }
      }
    }
  }
}

// ---------------- Kernel A3SC: phasor prep + all scans + ctx (fused) -------
__global__ __launch_bounds__(256, 4) void kernelA3SC(
    const short* __restrict__ Ybf, const float* __restrict__ pos,
    const float* __restrict__ poff, const float* __restrict__ b_mem1v,
    const float* __restrict__ b_key, const float* __restrict__ b_gate,
    const float* __restrict__ b_val,
    float* __restrict__ m1cT, float* __restrict__ m1sT,
    float* __restrict__ qc, float* __restrict__ qs,
    short* __restrict__ K2bf, short* __restrict__ gvT,
    float* __restrict__ sg, const float* __restrict__ x,
    float* __restrict__ ctxsum, short* __restrict__ ctxbf,
    unsigned* __restrict__ bar) {
  __shared__ float gsh[16];
  __shared__ float wsum[4];
  int blk = blockIdx.x, tid = threadIdx.x;
  // ---- Phase 1: A3 (16 tokens/block) ----
  if (blk < 512) {
    int tok0 = blk * 16;
#pragma unroll
    for (int h = 0; h < 2; ++h) {
      int t = h * 8 + (tid >> 5), p = tid & 31;
      int tok = tok0 + t, l = tok & (L_ - 1);
      int b = tok >> 11;
      float gate = 1.f / (1.f + expf(-(bf2f(Ybf[tok * 384 + 352]) + b_gate[0])));
      if (p == 0) {
        sg[tok] = gate;
        gsh[t] = gate;
      }
      float v1 = bf2f(Ybf[tok * 384 + 256 + p]) + b_mem1v[p];
      float ph = pos[l * 32 + p];
      float pc = cosf(ph), ps = sinf(ph);
      int idxT = (b * 32 + p) * L_ + l;
      m1cT[idxT] = pc * v1;
      m1sT[idxT] = ps * v1;
      float off = tanhf(bf2f(Ybf[tok * 384 + 288 + p]) + poff[l * 32 + p]) * PI_F;
      float oc = cosf(off), os = sinf(off);
      int idx = tok * 32 + p;
      qc[idx] = pc * oc - ps * os;
      qs[idx] = ps * oc + pc * os;
      float kp = tanhf(bf2f(Ybf[tok * 384 + 320 + p]) + b_key[p]) * PI_F;
      K2bf[tok * 64 + p] = f2bf(cosf(kp));
      K2bf[tok * 64 + 32 + p] = f2bf(sinf(kp));
    }
    __syncthreads();
    {
      int l0 = tok0 & (L_ - 1);
      int bc = (tok0 >> 11) * NC + (l0 >> 5);
      int tl0 = l0 & 31;  // 0 or 16
      short sv[16];
#pragma unroll
      for (int tt = 0; tt < 16; ++tt)
        sv[tt] = f2bf((bf2f(Ybf[(tok0 + tt) * 384 + tid]) + b_val[tid]) * gsh[tt]);
      int gb = (bc * 256 + tid) * 32 + tl0;
      *(short8_t*)&gvT[gb] = *(short8_t*)&sv[0];
      *(short8_t*)&gvT[gb + 8] = *(short8_t*)&sv[8];
    }
  }
  gbarf(bar, gridDim.x, 1u);
  // ---- Phase 2: scans + ctx chunk sums ----
  if (blk >= 260) {
    int c2 = blk - 260;
    int b = c2 >> 6, ch = c2 & 63;
    int xb = (b * L_ + ch * 32) * 256 + tid;
    float s = 0.f;
#pragma unroll 8
    for (int i = 0; i < 32; ++i) s += x[xb + i * 256];
    ctxsum[c2 * 256 + tid] = s;
  } else {
    int lane = tid & 63, wid = tid >> 6;
    float carry = 0.f;
    float* arr;
    int base;
    if (blk < 256) {
      arr = (blk < 128) ? m1cT : m1sT;
      base = (blk & 127) * L_;
    } else {
      arr = sg;
      base = (blk - 256) * L_;
    }
    for (int t0 = 0; t0 < L_; t0 += 256) {
      int l = t0 + tid;
      float v = arr[base + l];
#pragma unroll
      for (int off = 1; off < 64; off <<= 1) {
        float n = __shfl_up(v, off, 64);
        if (lane >= off) v += n;
      }
      if (lane == 63) wsum[wid] = v;
      __syncthreads();
      float add = carry;
      for (int w = 0; w < wid; ++w) add += wsum[w];
      arr[base + l] = v + add;
      carry += wsum[0] + wsum[1] + wsum[2] + wsum[3];
      __syncthreads();
    }
  }
  gbarf(bar, gridDim.x, 2u);
  // ---- Phase 3: ctx local scan -> ctxbf ----
  if (blk >= 260) {
    int c2 = blk - 260;
    int b = c2 >> 6, ch = c2 & 63;
    float run = 0.f;
    int sb = b * 64 * 256 + tid;
    for (int c = 0; c < ch; ++c) run += ctxsum[sb + c * 256];
    int xb = (b * L_ + ch * 32) * 256 + tid;
#pragma unroll 8
    for (int i = 0; i < 32; ++i) {
      run += x[xb + i * 256];
      int l = ch * 32 + i;
      ctxbf[xb + i * 256] = f2bf(run / (float)(l + 1));
    }
  }
}

// ---------------- Kernel KV: CD + E + FG fused (grid 256, 2 barriers) ------
__global__ __launch_bounds__(256) void kernelKV(
    const short* __restrict__ hs, const short* __restrict__ W2T,
    const float* __restrict__ b_sk2, const short* __restrict__ gvT,
    short* __restrict__ SPbf, short* __restrict__ UT,
    const short* __restrict__ K2bf, const float* __restrict__ sgc,
    const float* __restrict__ m1cT, const float* __restrict__ m1sT,
    const float* __restrict__ qc, const float* __restrict__ qs,
    const short* __restrict__ W1OT, const float* __restrict__ b_mem1o,
    const float* __restrict__ ln_g, const float* __restrict__ ln_b,
    short* __restrict__ cbn, unsigned* __restrict__ bar) {
  __shared__ __align__(16) char shm[38912];
  int blk = blockIdx.x, tid = threadIdx.x;
  int lane = tid & 63, w = tid >> 6;
  int ml = lane & 15, quad = lane >> 4, kq = quad * 8;
  // ---- Phase CD (blk < 128): sk2 phases + chunk U sums ----
  if (blk < 128) {
    short* SPL = (short*)shm;  // [2][64][40]
    int tok0 = blk * 64;
    int m0 = w * 16;
    floatx4 pacc[2] = {};
#pragma unroll
    for (int s = 0; s < 8; ++s) {
      short8_t a = *(const short8_t*)&hs[(tok0 + m0 + ml) * 256 + s * 32 + kq];
      short8_t b0 = *(const short8_t*)&W2T[ml * 256 + s * 32 + kq];
      short8_t b1 = *(const short8_t*)&W2T[(16 + ml) * 256 + s * 32 + kq];
      pacc[0] = __builtin_amdgcn_mfma_f32_16x16x32_bf16(a, b0, pacc[0], 0, 0, 0);
      pacc[1] = __builtin_amdgcn_mfma_f32_16x16x32_bf16(a, b1, pacc[1], 0, 0, 0);
    }
    int cl = w >> 1;
#pragma unroll
    for (int nt = 0; nt < 2; ++nt) {
      int p = nt * 16 + ml;
      float bs = b_sk2[p];
#pragma unroll
      for (int r = 0; r < 4; ++r) {
        int tok = tok0 + m0 + quad * 4 + r;
        float sp = tanhf(pacc[nt][r] + bs) * PI_F;
        short c = f2bf(cosf(sp)), s = f2bf(sinf(sp));
        int tl = (w & 1) * 16 + quad * 4 + r;
        SPL[(cl * 64 + p) * 40 + tl] = c;
        SPL[(cl * 64 + 32 + p) * 40 + tl] = s;
        SPbf[tok * 64 + p] = c;
        SPbf[tok * 64 + 32 + p] = s;
      }
    }
    __syncthreads();
    int c2 = w & 1, dbase = (w >> 1) * 128;
    int bc = blk * 2 + c2;
    short8_t a[4];
#pragma unroll
    for (int mt = 0; mt < 4; ++mt)
      a[mt] = *(short8_t*)&SPL[(c2 * 64 + mt * 16 + ml) * 40 + kq];
#pragma unroll
    for (int dp = 0; dp < 2; ++dp) {
      floatx4 acc[4][4] = {};
#pragma unroll
      for (int nt = 0; nt < 4; ++nt) {
        short8_t b = *(const short8_t*)&gvT[(bc * 256 + dbase + dp * 64 + nt * 16 + ml) * 32 + kq];
#pragma unroll
        for (int mt = 0; mt < 4; ++mt)
          acc[mt][nt] = __builtin_amdgcn_mfma_f32_16x16x32_bf16(a[mt], b, acc[mt][nt], 0, 0, 0);
      }
#pragma unroll
      for (int mt = 0; mt < 4; ++mt)
#pragma unroll
        for (int nt = 0; nt < 4; ++nt)
#pragma unroll
          for (int r = 0; r < 4; ++r) {
            int q = mt * 16 + quad * 4 + r;
            int d = dbase + dp * 64 + nt * 16 + ml;
            UT[(bc * 256 + d) * 64 + q] = f2bf(acc[mt][nt][r]);
          }
    }
  }
  gbarf(bar, gridDim.x, 1u);
  // ---- Phase E: exclusive chunk prefix (bf16, all 256 blocks) ----
  {
    int gt = blk * 256 + tid;
    int q = gt & 63;
    int d = (gt >> 6) & 255;
    int b = gt >> 14;
    int base = ((b * NC) * 256 + d) * 64 + q;
    const int cs = 256 * 64;
    float run = 0.f;
    for (int c0 = 0; c0 < NC; c0 += 8) {
      short v[8];
#pragma unroll
      for (int j = 0; j < 8; ++j) v[j] = UT[base + (c0 + j) * cs];
#pragma unroll
      for (int j = 0; j < 8; ++j) {
        UT[base + (c0 + j) * cs] = f2bf(run);
        run += bf2f(v[j]);
      }
    }
  }
  gbarf(bar, gridDim.x, 2u);
  // ---- Phase FG: retrieval + pos_out + LN -> cbn ----
  {
    short* SL = (short*)shm;                    // [32][40]
    short* PR = SL + 32 * 40;                   // [32][40]
    float* CMB = (float*)(shm + 5120);          // [32][260]
    float* scl = (float*)(shm + 5120 + 33280);  // [32]
    float* mu_s = scl + 32;
    float* rs_s = scl + 64;
    int bc = blk;
    int lbase = bc * CL;
    int bb = bc >> 6, lloc = (bc & 63) * 32;
    if (tid < 32) scl[tid] = rsqrtf(fmaxf(sgc[lbase + tid], 1.f)) * INV_SQRT_P;
    for (int it = 0; it < 4; ++it) {
      int i = it * 256 + tid;
      int p = i >> 5, t = i & 31;
      int gT = (bb * 32 + p) * L_ + lloc + t;
      int g = (lbase + t) * 32 + p;
      PR[t * 40 + p] = f2bf((m1cT[gT] * qc[g] + m1sT[gT] * qs[g]) * INV_SQRT_P);
    }
    floatx4 acc[2][4] = {};
    short8_t ka0 = *(const short8_t*)&K2bf[(lbase + ml) * 64 + kq];
    short8_t ka1 = *(const short8_t*)&K2bf[(lbase + 16 + ml) * 64 + kq];
    short8_t kb0 = *(const short8_t*)&K2bf[(lbase + ml) * 64 + 32 + kq];
    short8_t kb1 = *(const short8_t*)&K2bf[(lbase + 16 + ml) * 64 + 32 + kq];
#pragma unroll
    for (int nt = 0; nt < 4; ++nt) {
      short8_t b = *(const short8_t*)&UT[(bc * 256 + w * 64 + nt * 16 + ml) * 64 + kq];
      acc[0][nt] = __builtin_amdgcn_mfma_f32_16x16x32_bf16(ka0, b, acc[0][nt], 0, 0, 0);
      acc[1][nt] = __builtin_amdgcn_mfma_f32_16x16x32_bf16(ka1, b, acc[1][nt], 0, 0, 0);
    }
    if (w == 0) {
      floatx4 sacc[2][2] = {};
#pragma unroll
      for (int ks2 = 0; ks2 < 2; ++ks2) {
        short8_t a0 = (ks2 == 0) ? ka0 : kb0;
        short8_t a1 = (ks2 == 0) ? ka1 : kb1;
        short8_t b0 = *(const short8_t*)&SPbf[(lbase + ml) * 64 + ks2 * 32 + kq];
        short8_t b1 = *(const short8_t*)&SPbf[(lbase + 16 + ml) * 64 + ks2 * 32 + kq];
        sacc[0][0] = __builtin_amdgcn_mfma_f32_16x16x32_bf16(a0, b0, sacc[0][0], 0, 0, 0);
        sacc[0][1] = __builtin_amdgcn_mfma_f32_16x16x32_bf16(a0, b1, sacc[0][1], 0, 0, 0);
        sacc[1][0] = __builtin_amdgcn_mfma_f32_16x16x32_bf16(a1, b0, sacc[1][0], 0, 0, 0);
        sacc[1][1] = __builtin_amdgcn_mfma_f32_16x16x32_bf16(a1, b1, sacc[1][1], 0, 0, 0);
      }
#pragma unroll
      for (int mt = 0; mt < 2; ++mt)
#pragma unroll
        for (int nt = 0; nt < 2; ++nt)
#pragma unroll
          for (int r = 0; r < 4; ++r) {
            int trow = mt * 16 + quad * 4 + r;
            int scol = nt * 16 + ml;
            float v = (scol <= trow) ? sacc[mt][nt][r] : 0.f;
            SL[trow * 40 + scol] = f2bf(v);
          }
    }
    __syncthreads();
#pragma unroll
    for (int nt = 0; nt < 4; ++nt) {
      short8_t b = *(const short8_t*)&UT[(bc * 256 + w * 64 + nt * 16 + ml) * 64 + 32 + kq];
      acc[0][nt] = __builtin_amdgcn_mfma_f32_16x16x32_bf16(kb0, b, acc[0][nt], 0, 0, 0);
      acc[1][nt] = __builtin_amdgcn_mfma_f32_16x16x32_bf16(kb1, b, acc[1][nt], 0, 0, 0);
    }
    {
      short8_t a0 = *(short8_t*)&SL[ml * 40 + kq];
      short8_t a1 = *(short8_t*)&SL[(16 + ml) * 40 + kq];
#pragma unroll
      for (int nt = 0; nt < 4; ++nt) {
        short8_t b = *(const short8_t*)&gvT[(bc * 256 + w * 64 + nt * 16 + ml) * 32 + kq];
        acc[0][nt] = __builtin_amdgcn_mfma_f32_16x16x32_bf16(a0, b, acc[0][nt], 0, 0, 0);
        acc[1][nt] = __builtin_amdgcn_mfma_f32_16x16x32_bf16(a1, b, acc[1][nt], 0, 0, 0);
      }
    }
    floatx4 macc[2][4] = {};
    {
      short8_t a0 = *(short8_t*)&PR[ml * 40 + kq];
      short8_t a1 = *(short8_t*)&PR[(16 + ml) * 40 + kq];
#pragma unroll
      for (int nt = 0; nt < 4; ++nt) {
        short8_t b = *(const short8_t*)&W1OT[(w * 64 + nt * 16 + ml) * 32 + kq];
        macc[0][nt] = __builtin_amdgcn_mfma_f32_16x16x32_bf16(a0, b, macc[0][nt], 0, 0, 0);
        macc[1][nt] = __builtin_amdgcn_mfma_f32_16x16x32_bf16(a1, b, macc[1][nt], 0, 0, 0);
      }
    }
#pragma unroll
    for (int mt = 0; mt < 2; ++mt)
#pragma unroll
      for (int nt = 0; nt < 4; ++nt) {
        int d = w * 64 + nt * 16 + ml;
        float bm = b_mem1o[d];
#pragma unroll
        for (int r = 0; r < 4; ++r) {
          int t = mt * 16 + quad * 4 + r;
          CMB[t * 260 + d] = acc[mt][nt][r] * scl[t] + macc[mt][nt][r] + bm;
        }
      }
    __syncthreads();
    {
      int t = tid >> 3, g = tid & 7;
      float s = 0.f, s2 = 0.f;
#pragma unroll
      for (int j = 0; j < 32; ++j) {
        float v = CMB[t * 260 + g + j * 8];
        s += v;
        s2 += v * v;
      }
#pragma unroll
      for (int m = 1; m < 8; m <<= 1) {
        s += __shfl_xor(s, m, 64);
        s2 += __shfl_xor(s2, m, 64);
      }
      if (g == 0) {
        float mu = s / (float)D_;
        float var = s2 / (float)D_ - mu * mu;
        mu_s[t] = mu;
        rs_s[t] = rsqrtf(var + 1e-5f);
      }
    }
    __syncthreads();
    {
      float lg = ln_g[tid], lb = ln_b[tid];
#pragma unroll
      for (int t = 0; t < 32; ++t)
        cbn[(lbase + t) * 256 + tid] =
            f2bf((CMB[t * 260 + tid] - mu_s[t]) * rs_s[t] * lg + lb);
    }
  }
}

extern "C" void kernel_launch(void* const* d_in, const int* in_sizes, int n_in,
                              void* d_out, int out_size, void* d_ws, size_t ws_size,
                              hipStream_t stream) {
  const float* x = (const float*)d_in[0];
  const float* pos = (const float*)d_in[1];
  const float* w_mem1v = (const float*)d_in[2];
  const float* b_mem1v = (const float*)d_in[3];
  const float* w_mem1o = (const float*)d_in[4];
  const float* b_mem1o = (const float*)d_in[5];
  const float* w_off = (const float*)d_in[6];
  const float* b_off = (const float*)d_in[7];
  const float* w_key = (const float*)d_in[8];
  const float* b_key = (const float*)d_in[9];
  const float* w_val = (const float*)d_in[10];
  const float* b_val = (const float*)d_in[11];
  const float* w_sk1 = (const float*)d_in[12];
  const float* b_sk1 = (const float*)d_in[13];
  const float* w_sk2 = (const float*)d_in[14];
  const float* b_sk2 = (const float*)d_in[15];
  const float* w_gate = (const float*)d_in[16];
  const float* b_gate = (const float*)d_in[17];
  const float* ln_g = (const float*)d_in[18];
  const float* ln_b = (const float*)d_in[19];
  const float* w_out = (const float*)d_in[20];
  const float* b_out = (const float*)d_in[21];
  float* out = (float*)d_out;
  float* ws = (float*)d_ws;

  const int BLP = B_ * L_ * P_;  // 262144
  const int BLD = B_ * L_ * D_;  // 2097152
  float* m1cT = ws;
  float* m1sT = m1cT + BLP;
  float* qc = m1sT + BLP;
  float* qs = qc + BLP;
  float* sg = qs + BLP;
  float* poff = sg + B_ * L_;
  float* ctxsum = poff + L_ * P_;
  short* Ybf = (short*)(ctxsum + B_ * 64 * 256);
  short* UT = Ybf;  // aliases Ybf (dead after A3SC)
  short* xbf = UT + (size_t)B_ * NC * 256 * 64;
  short* cbn = xbf;  // aliases xbf (dead after gemm1)
  short* ctxbf = xbf + BLD;
  short* hs = ctxbf + BLD;
  short* gvT = hs + BLD;
  short* K2bf = gvT + BLD;
  short* SPbf = K2bf + B_ * L_ * 64;
  short* WA = SPbf + B_ * L_ * 64;
  short* W1 = WA + 384 * 256;
  short* WO = W1 + 256 * 512;
  short* W2T = WO + 256 * 256;
  short* W1OT = W2T + 32 * 256;
  unsigned* barA = (unsigned*)(W1OT + 256 * 32);  // 516 flags (A3SC)
  unsigned* barK = barA + 516;                     // 256 flags (KV)

  wprep<<<3520, 256, 0, stream>>>(x, pos, w_val, w_mem1v, w_off, b_off, w_key, w_gate,
                                  w_sk1, w_out, w_sk2, w_mem1o, WA, W1, WO, W2T, W1OT,
                                  xbf, poff, barA);
  gemm_k<2, 6, 0><<<128 * 6, 256, 0, stream>>>(xbf, nullptr, WA, nullptr, nullptr, nullptr, Ybf);
  kernelA3SC<<<516, 256, 0, stream>>>(Ybf, pos, poff, b_mem1v, b_key, b_gate, b_val,
                                      m1cT, m1sT, qc, qs, K2bf, gvT, sg, x, ctxsum,
                                      ctxbf, barA);
  gemm_k<4, 4, 1><<<128 * 4, 256, 0, stream>>>(xbf, ctxbf, W1, b_sk1, nullptr, nullptr, hs);
  kernelKV<<<256, 256, 0, stream>>>(hs, W2T, b_sk2, gvT, SPbf, UT, K2bf, sg,
                                    m1cT, m1sT, qc, qs, W1OT, b_mem1o, ln_g, ln_b,
                                    cbn, barK);
  gemm_k<2, 4, 2><<<128 * 4, 256, 0, stream>>>(cbn, nullptr, WO, b_out, x, out, nullptr);
}

// Round 10
// 208.372 us; speedup vs baseline: 2.1306x; 1.7364x over previous
//
#include <hip/hip_runtime.h>
#include <hip/hip_bf16.h>

constexpr int B_ = 4;
constexpr int L_ = 2048;
constexpr int D_ = 256;
constexpr int P_ = 32;
constexpr int CL = 32;
constexpr int NC = L_ / CL;  // 64

#define PI_F 3.14159265358979323846f
#define INV_SQRT_P 0.17677669529663687f

typedef __attribute__((ext_vector_type(8))) short short8_t;
typedef __attribute__((ext_vector_type(4))) float floatx4;

static __device__ inline short f2bf(float f) {
  unsigned int u;
  __builtin_memcpy(&u, &f, 4);
  unsigned int r = (u + 0x7fffu + ((u >> 16) & 1u)) >> 16;
  return (short)r;
}
static __device__ inline float bf2f(short s) {
  unsigned int u = ((unsigned int)(unsigned short)s) << 16;
  float f;
  __builtin_memcpy(&f, &u, 4);
  return f;
}

// B-fragment (16x16x32, layout [n=ml][k=quad*8+j]) from fp32 [k][NCOLS] weight.
// k0 must already include quad*8. nloc = n-base + ml.
template <int NCOLS>
static __device__ inline short8_t loadBfragF32(const float* __restrict__ W,
                                               int k0, int nloc) {
  short s[8];
#pragma unroll
  for (int j = 0; j < 8; ++j) s[j] = f2bf(W[(k0 + j) * NCOLS + nloc]);
  return *(short8_t*)s;
}

// A-fragment (lane holds A[m][k0..k0+7]) from fp32 row-major [m][256].
static __device__ inline short8_t loadAfragF32(const float* __restrict__ X,
                                               int row, int k0) {
  float4 v0 = *(const float4*)&X[row * 256 + k0];
  float4 v1 = *(const float4*)&X[row * 256 + k0 + 4];
  short s[8] = {f2bf(v0.x), f2bf(v0.y), f2bf(v0.z), f2bf(v0.w),
                f2bf(v1.x), f2bf(v1.y), f2bf(v1.z), f2bf(v1.w)};
  return *(short8_t*)s;
}

// ---------------- Kernel A3G: gemm0 + phasor prep + ctx chunk sums ---------
// Block = 1 chunk (32 tokens). Y kept in LDS fp32, never global.
__global__ __launch_bounds__(256) void kernelA3G(
    const float* __restrict__ x, const float* __restrict__ pos,
    const float* __restrict__ w_val, const float* __restrict__ w_mem1v,
    const float* __restrict__ w_off, const float* __restrict__ w_key,
    const float* __restrict__ w_gate, const float* __restrict__ b_mem1v,
    const float* __restrict__ b_off, const float* __restrict__ b_key,
    const float* __restrict__ b_gate, const float* __restrict__ b_val,
    float* __restrict__ m1cT, float* __restrict__ m1sT,
    float* __restrict__ qc, float* __restrict__ qs,
    short* __restrict__ K2bf, short* __restrict__ gvT,
    float* __restrict__ sg, float* __restrict__ ctxsum) {
  __shared__ float Yl[32][390];  // ~49.9 KB
  __shared__ float gsh[32];
  int tid = threadIdx.x;
  int bc = blockIdx.x;
  int b = bc >> 6;
  int lbase = bc * 32;  // global token base
  int lane = tid & 63, w = tid >> 6;
  int ml = lane & 15, quad = lane >> 4, kq = quad * 8;

  // ---- Phase A: Y[32][384] = x @ [w_val|w_mem1v|w_off_x|w_key|w_gate] ----
  floatx4 acc[2][6] = {};
  const float* xrow = x + (size_t)lbase * 256;
  for (int ks = 0; ks < 8; ++ks) {
    int k0 = ks * 32 + kq;
    short8_t a0 = loadAfragF32(xrow, ml, k0);
    short8_t a1 = loadAfragF32(xrow, 16 + ml, k0);
#pragma unroll
    for (int nt = 0; nt < 6; ++nt) {
      int n = w * 96 + nt * 16;
      if (n > 352) continue;
      short8_t bfr;
      if (n < 256) bfr = loadBfragF32<256>(w_val, k0, n + ml);
      else if (n < 288) bfr = loadBfragF32<32>(w_mem1v, k0, n - 256 + ml);
      else if (n < 320) bfr = loadBfragF32<32>(w_off, k0, n - 288 + ml);
      else if (n < 352) bfr = loadBfragF32<32>(w_key, k0, n - 320 + ml);
      else {
        short s[8];
#pragma unroll
        for (int j = 0; j < 8; ++j) s[j] = (ml == 0) ? f2bf(w_gate[k0 + j]) : (short)0;
        bfr = *(short8_t*)s;
      }
      acc[0][nt] = __builtin_amdgcn_mfma_f32_16x16x32_bf16(a0, bfr, acc[0][nt], 0, 0, 0);
      acc[1][nt] = __builtin_amdgcn_mfma_f32_16x16x32_bf16(a1, bfr, acc[1][nt], 0, 0, 0);
    }
  }
#pragma unroll
  for (int nt = 0; nt < 6; ++nt) {
    int n = w * 96 + nt * 16;
    if (n > 352) continue;
#pragma unroll
    for (int mt = 0; mt < 2; ++mt)
#pragma unroll
      for (int r = 0; r < 4; ++r)
        Yl[mt * 16 + quad * 4 + r][n + ml] = acc[mt][nt][r];
  }
  __syncthreads();

  // ---- Phase B: per-(t,p) phasor prep ----
  for (int h = 0; h < 4; ++h) {
    int t = h * 8 + (tid >> 5), p = tid & 31;
    int tok = lbase + t, l = tok & (L_ - 1);
    float gate = 1.f / (1.f + expf(-(Yl[t][352] + b_gate[0])));
    if (p == 0) {
      sg[tok] = gate;
      gsh[t] = gate;
    }
    float v1 = Yl[t][256 + p] + b_mem1v[p];
    float ph = pos[l * 32 + p];
    float pc = cosf(ph), ps = sinf(ph);
    m1cT[(b * 32 + p) * L_ + l] = pc * v1;
    m1sT[(b * 32 + p) * L_ + l] = ps * v1;
    float a = b_off[p];
    for (int j = 0; j < 32; ++j) a += pos[l * 32 + j] * w_off[(256 + j) * 32 + p];
    float off = tanhf(Yl[t][288 + p] + a) * PI_F;
    float oc = cosf(off), os = sinf(off);
    int idx = tok * 32 + p;
    qc[idx] = pc * oc - ps * os;
    qs[idx] = ps * oc + pc * os;
    float kp = tanhf(Yl[t][320 + p] + b_key[p]) * PI_F;
    K2bf[tok * 64 + p] = f2bf(cosf(kp));
    K2bf[tok * 64 + 32 + p] = f2bf(sinf(kp));
  }
  __syncthreads();

  // ---- Phase C: gvT (bf16, [d][t]) + ctx chunk sums ----
  {
    int d = tid;
    float bv = b_val[d];
    float cs = 0.f;
    short sv[32];
#pragma unroll 8
    for (int t = 0; t < 32; ++t) {
      cs += x[(size_t)(lbase + t) * 256 + d];
      sv[t] = f2bf((Yl[t][d] + bv) * gsh[t]);
    }
    ctxsum[bc * 256 + d] = cs;
    int gb = (bc * 256 + d) * 32;
    *(short8_t*)&gvT[gb] = *(short8_t*)&sv[0];
    *(short8_t*)&gvT[gb + 8] = *(short8_t*)&sv[8];
    *(short8_t*)&gvT[gb + 16] = *(short8_t*)&sv[16];
    *(short8_t*)&gvT[gb + 24] = *(short8_t*)&sv[24];
  }
}

// ---------------- scan_all: m1 scans + sg scan + ctx local scan ------------
// blk<256: m1 rows; 256..259: sg; 260..515: ctx local scan -> ctxbf.
__global__ void scan_all(float* __restrict__ m1cT, float* __restrict__ m1sT,
                         float* __restrict__ sg, const float* __restrict__ x,
                         const float* __restrict__ ctxsum, short* __restrict__ ctxbf) {
  int blk = blockIdx.x;
  int tid = threadIdx.x;
  if (blk >= 260) {
    int c2 = blk - 260;
    int b = c2 >> 6, ch = c2 & 63;
    float run = 0.f;
    int sb = b * 64 * 256 + tid;
    for (int c = 0; c < ch; ++c) run += ctxsum[sb + c * 256];
    int xb = (b * L_ + ch * 32) * 256 + tid;
#pragma unroll 8
    for (int i = 0; i < 32; ++i) {
      run += x[xb + i * 256];
      int l = ch * 32 + i;
      ctxbf[xb + i * 256] = f2bf(run / (float)(l + 1));
    }
    return;
  }
  int lane = tid & 63, wid = tid >> 6;
  __shared__ float wsum[4];
  float carry = 0.f;
  float* arr;
  int base;
  if (blk < 256) {
    arr = (blk < 128) ? m1cT : m1sT;
    base = (blk & 127) * L_;
  } else {
    arr = sg;
    base = (blk - 256) * L_;
  }
  for (int t0 = 0; t0 < L_; t0 += 256) {
    int l = t0 + tid;
    float v = arr[base + l];
#pragma unroll
    for (int off = 1; off < 64; off <<= 1) {
      float n = __shfl_up(v, off, 64);
      if (lane >= off) v += n;
    }
    if (lane == 63) wsum[wid] = v;
    __syncthreads();
    float add = carry;
    for (int w = 0; w < wid; ++w) add += wsum[w];
    arr[base + l] = v + add;
    carry += wsum[0] + wsum[1] + wsum[2] + wsum[3];
    __syncthreads();
  }
}

// ---------------- Kernel CDg: gemm1 (sk1) + sk2 phases + chunk U sums ------
// Block = 1 chunk (32 tokens). hs lives only in LDS.
__global__ __launch_bounds__(256) void kernelCDg(
    const float* __restrict__ x, const short* __restrict__ ctxbf,
    const float* __restrict__ w_sk1, const float* __restrict__ b_sk1,
    const float* __restrict__ w_sk2, const float* __restrict__ b_sk2,
    const short* __restrict__ gvT, short* __restrict__ SPbf,
    short* __restrict__ UT) {
  __shared__ __align__(16) short hsl[32][264];  // ~16.9 KB
  __shared__ __align__(16) short SPL[64][40];   // ~5.1 KB
  int tid = threadIdx.x;
  int bc = blockIdx.x;
  int lbase = bc * 32;
  int lane = tid & 63, w = tid >> 6;
  int ml = lane & 15, quad = lane >> 4, kq = quad * 8;

  // ---- Phase 1: hs = gelu([x|ctx] @ w_sk1 + b_sk1) ----
  floatx4 acc[2][4] = {};
  const float* xrow = x + (size_t)lbase * 256;
  for (int ks = 0; ks < 16; ++ks) {
    int k0 = ks * 32 + kq;
    short8_t a0, a1;
    if (ks < 8) {
      a0 = loadAfragF32(xrow, ml, k0);
      a1 = loadAfragF32(xrow, 16 + ml, k0);
    } else {
      a0 = *(const short8_t*)&ctxbf[(size_t)(lbase + ml) * 256 + (k0 - 256)];
      a1 = *(const short8_t*)&ctxbf[(size_t)(lbase + 16 + ml) * 256 + (k0 - 256)];
    }
#pragma unroll
    for (int nt = 0; nt < 4; ++nt) {
      short8_t bfr = loadBfragF32<256>(w_sk1, k0, w * 64 + nt * 16 + ml);
      acc[0][nt] = __builtin_amdgcn_mfma_f32_16x16x32_bf16(a0, bfr, acc[0][nt], 0, 0, 0);
      acc[1][nt] = __builtin_amdgcn_mfma_f32_16x16x32_bf16(a1, bfr, acc[1][nt], 0, 0, 0);
    }
  }
#pragma unroll
  for (int nt = 0; nt < 4; ++nt) {
    int n = w * 64 + nt * 16 + ml;
    float bs = b_sk1[n];
#pragma unroll
    for (int mt = 0; mt < 2; ++mt)
#pragma unroll
      for (int r = 0; r < 4; ++r) {
        float v = acc[mt][nt][r] + bs;
        float g = 0.5f * v * (1.f + erff(v * 0.70710678118654752f));
        hsl[mt * 16 + quad * 4 + r][n] = f2bf(g);
      }
  }
  __syncthreads();

  // ---- Phase 2: storage phases (sk2) ----
  {
    int m0 = (w & 1) * 16, n0 = (w >> 1) * 16;
    floatx4 pacc = {};
#pragma unroll
    for (int ks = 0; ks < 8; ++ks) {
      int k0 = ks * 32 + kq;
      short8_t a = *(short8_t*)&hsl[m0 + ml][k0];
      short8_t bfr = loadBfragF32<32>(w_sk2, k0, n0 + ml);
      pacc = __builtin_amdgcn_mfma_f32_16x16x32_bf16(a, bfr, pacc, 0, 0, 0);
    }
    int p = n0 + ml;
    float bs = b_sk2[p];
#pragma unroll
    for (int r = 0; r < 4; ++r) {
      int tl = m0 + quad * 4 + r;
      int tok = lbase + tl;
      float sp = tanhf(pacc[r] + bs) * PI_F;
      short c = f2bf(cosf(sp)), s = f2bf(sinf(sp));
      SPL[p][tl] = c;
      SPL[32 + p][tl] = s;
      SPbf[tok * 64 + p] = c;
      SPbf[tok * 64 + 32 + p] = s;
    }
  }
  __syncthreads();

  // ---- Phase 3: U_chunk[64 q][256 d] = SPL @ gv ----
  short8_t a[4];
#pragma unroll
  for (int mt = 0; mt < 4; ++mt) a[mt] = *(short8_t*)&SPL[mt * 16 + ml][kq];
  floatx4 uacc[4][4] = {};
#pragma unroll
  for (int nt = 0; nt < 4; ++nt) {
    short8_t bfr = *(const short8_t*)&gvT[(bc * 256 + w * 64 + nt * 16 + ml) * 32 + kq];
#pragma unroll
    for (int mt = 0; mt < 4; ++mt)
      uacc[mt][nt] = __builtin_amdgcn_mfma_f32_16x16x32_bf16(a[mt], bfr, uacc[mt][nt], 0, 0, 0);
  }
#pragma unroll
  for (int mt = 0; mt < 4; ++mt)
#pragma unroll
    for (int nt = 0; nt < 4; ++nt)
#pragma unroll
      for (int r = 0; r < 4; ++r) {
        int q = mt * 16 + quad * 4 + r;
        int d = w * 64 + nt * 16 + ml;
        UT[(bc * 256 + d) * 64 + q] = f2bf(uacc[mt][nt][r]);
      }
}

// ---------------- Kernel E: exclusive chunk prefix over UT (bf16) ----------
__global__ void kernelE(short* __restrict__ UT) {
  int gt = blockIdx.x * 256 + threadIdx.x;  // B*256d*64q = 65536
  int q = gt & 63;
  int d = (gt >> 6) & 255;
  int b = gt >> 14;
  int base = ((b * NC) * 256 + d) * 64 + q;
  const int cs = 256 * 64;
  float run = 0.f;
  for (int c0 = 0; c0 < NC; c0 += 8) {
    short v[8];
#pragma unroll
    for (int j = 0; j < 8; ++j) v[j] = UT[base + (c0 + j) * cs];
#pragma unroll
    for (int j = 0; j < 8; ++j) {
      UT[base + (c0 + j) * cs] = f2bf(run);
      run += bf2f(v[j]);
    }
  }
}

// ---------------- Kernel FGO: retrieval + pos_out + LN + output GEMM -------
__global__ __launch_bounds__(256) void kernelFGO(
    const short* __restrict__ UT, const short* __restrict__ SPbf,
    const short* __restrict__ K2bf, const short* __restrict__ gvT,
    const float* __restrict__ sgc, const float* __restrict__ m1cT,
    const float* __restrict__ m1sT, const float* __restrict__ qc,
    const float* __restrict__ qs, const float* __restrict__ w_mem1o,
    const float* __restrict__ b_mem1o, const float* __restrict__ ln_g,
    const float* __restrict__ ln_b, const float* __restrict__ x,
    const float* __restrict__ w_out, const float* __restrict__ b_out,
    float* __restrict__ out) {
  __shared__ __align__(16) short SL[32][40];
  __shared__ __align__(16) short PR[32][40];
  __shared__ float CMB[32][260];
  __shared__ __align__(16) short CBN[32][264];
  __shared__ float scl[32], mu_s[32], rs_s[32];
  int tid = threadIdx.x;
  int bc = blockIdx.x;
  int lbase = bc * CL;
  int bb = bc >> 6, lloc = (bc & 63) * 32;
  int lane = tid & 63, w = tid >> 6;
  int ml = lane & 15, quad = lane >> 4, kq = quad * 8;
  if (tid < 32) scl[tid] = rsqrtf(fmaxf(sgc[lbase + tid], 1.f)) * INV_SQRT_P;
  for (int it = 0; it < 4; ++it) {
    int i = it * 256 + tid;
    int p = i >> 5, t = i & 31;
    int gT = (bb * 32 + p) * L_ + lloc + t;
    int g = (lbase + t) * 32 + p;
    PR[t][p] = f2bf((m1cT[gT] * qc[g] + m1sT[gT] * qs[g]) * INV_SQRT_P);
  }
  floatx4 acc[2][4] = {};
  short8_t ka0 = *(const short8_t*)&K2bf[(lbase + ml) * 64 + kq];
  short8_t ka1 = *(const short8_t*)&K2bf[(lbase + 16 + ml) * 64 + kq];
  short8_t kb0 = *(const short8_t*)&K2bf[(lbase + ml) * 64 + 32 + kq];
  short8_t kb1 = *(const short8_t*)&K2bf[(lbase + 16 + ml) * 64 + 32 + kq];
#pragma unroll
  for (int nt = 0; nt < 4; ++nt) {
    short8_t b = *(const short8_t*)&UT[(bc * 256 + w * 64 + nt * 16 + ml) * 64 + kq];
    acc[0][nt] = __builtin_amdgcn_mfma_f32_16x16x32_bf16(ka0, b, acc[0][nt], 0, 0, 0);
    acc[1][nt] = __builtin_amdgcn_mfma_f32_16x16x32_bf16(ka1, b, acc[1][nt], 0, 0, 0);
  }
  if (w == 0) {
    floatx4 sacc[2][2] = {};
#pragma unroll
    for (int ks2 = 0; ks2 < 2; ++ks2) {
      short8_t a0 = (ks2 == 0) ? ka0 : kb0;
      short8_t a1 = (ks2 == 0) ? ka1 : kb1;
      short8_t b0 = *(const short8_t*)&SPbf[(lbase + ml) * 64 + ks2 * 32 + kq];
      short8_t b1 = *(const short8_t*)&SPbf[(lbase + 16 + ml) * 64 + ks2 * 32 + kq];
      sacc[0][0] = __builtin_amdgcn_mfma_f32_16x16x32_bf16(a0, b0, sacc[0][0], 0, 0, 0);
      sacc[0][1] = __builtin_amdgcn_mfma_f32_16x16x32_bf16(a0, b1, sacc[0][1], 0, 0, 0);
      sacc[1][0] = __builtin_amdgcn_mfma_f32_16x16x32_bf16(a1, b0, sacc[1][0], 0, 0, 0);
      sacc[1][1] = __builtin_amdgcn_mfma_f32_16x16x32_bf16(a1, b1, sacc[1][1], 0, 0, 0);
    }
#pragma unroll
    for (int mt = 0; mt < 2; ++mt)
#pragma unroll
      for (int nt = 0; nt < 2; ++nt)
#pragma unroll
        for (int r = 0; r < 4; ++r) {
          int trow = mt * 16 + quad * 4 + r;
          int scol = nt * 16 + ml;
          float v = (scol <= trow) ? sacc[mt][nt][r] : 0.f;
          SL[trow][scol] = f2bf(v);
        }
  }
  __syncthreads();
#pragma unroll
  for (int nt = 0; nt < 4; ++nt) {
    short8_t b = *(const short8_t*)&UT[(bc * 256 + w * 64 + nt * 16 + ml) * 64 + 32 + kq];
    acc[0][nt] = __builtin_amdgcn_mfma_f32_16x16x32_bf16(kb0, b, acc[0][nt], 0, 0, 0);
    acc[1][nt] = __builtin_amdgcn_mfma_f32_16x16x32_bf16(kb1, b, acc[1][nt], 0, 0, 0);
  }
  {
    short8_t a0 = *(short8_t*)&SL[ml][kq];
    short8_t a1 = *(short8_t*)&SL[16 + ml][kq];
#pragma unroll
    for (int nt = 0; nt < 4; ++nt) {
      short8_t b = *(const short8_t*)&gvT[(bc * 256 + w * 64 + nt * 16 + ml) * 32 + kq];
      acc[0][nt] = __builtin_amdgcn_mfma_f32_16x16x32_bf16(a0, b, acc[0][nt], 0, 0, 0);
      acc[1][nt] = __builtin_amdgcn_mfma_f32_16x16x32_bf16(a1, b, acc[1][nt], 0, 0, 0);
    }
  }
  floatx4 macc[2][4] = {};
  {
    short8_t a0 = *(short8_t*)&PR[ml][kq];
    short8_t a1 = *(short8_t*)&PR[16 + ml][kq];
#pragma unroll
    for (int nt = 0; nt < 4; ++nt) {
      short8_t b = loadBfragF32<256>(w_mem1o, kq, w * 64 + nt * 16 + ml);
      macc[0][nt] = __builtin_amdgcn_mfma_f32_16x16x32_bf16(a0, b, macc[0][nt], 0, 0, 0);
      macc[1][nt] = __builtin_amdgcn_mfma_f32_16x16x32_bf16(a1, b, macc[1][nt], 0, 0, 0);
    }
  }
#pragma unroll
  for (int mt = 0; mt < 2; ++mt)
#pragma unroll
    for (int nt = 0; nt < 4; ++nt) {
      int d = w * 64 + nt * 16 + ml;
      float bm = b_mem1o[d];
#pragma unroll
      for (int r = 0; r < 4; ++r) {
        int t = mt * 16 + quad * 4 + r;
        CMB[t][d] = acc[mt][nt][r] * scl[t] + macc[mt][nt][r] + bm;
      }
    }
  __syncthreads();
  {
    int t = tid >> 3, g = tid & 7;
    float s = 0.f, s2 = 0.f;
#pragma unroll
    for (int j = 0; j < 32; ++j) {
      float v = CMB[t][g + j * 8];
      s += v;
      s2 += v * v;
    }
#pragma unroll
    for (int m = 1; m < 8; m <<= 1) {
      s += __shfl_xor(s, m, 64);
      s2 += __shfl_xor(s2, m, 64);
    }
    if (g == 0) {
      float mu = s / (float)D_;
      float var = s2 / (float)D_ - mu * mu;
      mu_s[t] = mu;
      rs_s[t] = rsqrtf(var + 1e-5f);
    }
  }
  __syncthreads();
  {
    float lg = ln_g[tid], lb = ln_b[tid];
#pragma unroll
    for (int t = 0; t < 32; ++t)
      CBN[t][tid] = f2bf((CMB[t][tid] - mu_s[t]) * rs_s[t] * lg + lb);
  }
  __syncthreads();
  // ---- output GEMM: out = x + CBN @ w_out + b_out ----
  floatx4 oacc[2][4] = {};
  for (int ks = 0; ks < 8; ++ks) {
    int k0 = ks * 32 + kq;
    short8_t a0 = *(short8_t*)&CBN[ml][k0];
    short8_t a1 = *(short8_t*)&CBN[16 + ml][k0];
#pragma unroll
    for (int nt = 0; nt < 4; ++nt) {
      short8_t b = loadBfragF32<256>(w_out, k0, w * 64 + nt * 16 + ml);
      oacc[0][nt] = __builtin_amdgcn_mfma_f32_16x16x32_bf16(a0, b, oacc[0][nt], 0, 0, 0);
      oacc[1][nt] = __builtin_amdgcn_mfma_f32_16x16x32_bf16(a1, b, oacc[1][nt], 0, 0, 0);
    }
  }
#pragma unroll
  for (int nt = 0; nt < 4; ++nt) {
    int n = w * 64 + nt * 16 + ml;
    float bo = b_out[n];
#pragma unroll
    for (int mt = 0; mt < 2; ++mt)
#pragma unroll
      for (int r = 0; r < 4; ++r) {
        int tok = lbase + mt * 16 + quad * 4 + r;
        out[(size_t)tok * 256 + n] = x[(size_t)tok * 256 + n] + oacc[mt][nt][r] + bo;
      }
  }
}

extern "C" void kernel_launch(void* const* d_in, const int* in_sizes, int n_in,
                              void* d_out, int out_size, void* d_ws, size_t ws_size,
                              hipStream_t stream) {
  const float* x = (const float*)d_in[0];
  const float* pos = (const float*)d_in[1];
  const float* w_mem1v = (const float*)d_in[2];
  const float* b_mem1v = (const float*)d_in[3];
  const float* w_mem1o = (const float*)d_in[4];
  const float* b_mem1o = (const float*)d_in[5];
  const float* w_off = (const float*)d_in[6];
  const float* b_off = (const float*)d_in[7];
  const float* w_key = (const float*)d_in[8];
  const float* b_key = (const float*)d_in[9];
  const float* w_val = (const float*)d_in[10];
  const float* b_val = (const float*)d_in[11];
  const float* w_sk1 = (const float*)d_in[12];
  const float* b_sk1 = (const float*)d_in[13];
  const float* w_sk2 = (const float*)d_in[14];
  const float* b_sk2 = (const float*)d_in[15];
  const float* w_gate = (const float*)d_in[16];
  const float* b_gate = (const float*)d_in[17];
  const float* ln_g = (const float*)d_in[18];
  const float* ln_b = (const float*)d_in[19];
  const float* w_out = (const float*)d_in[20];
  const float* b_out = (const float*)d_in[21];
  float* out = (float*)d_out;
  float* ws = (float*)d_ws;

  const int BLP = B_ * L_ * P_;  // 262144
  const int BLD = B_ * L_ * D_;  // 2097152
  float* m1cT = ws;
  float* m1sT = m1cT + BLP;
  float* qc = m1sT + BLP;
  float* qs = qc + BLP;
  float* sg = qs + BLP;
  float* ctxsum = sg + B_ * L_;             // B*64*256
  short* ctxbf = (short*)(ctxsum + B_ * 64 * 256);  // BLD shorts
  short* gvT = ctxbf + BLD;                 // BLD shorts
  short* K2bf = gvT + BLD;                  // B*L*64
  short* SPbf = K2bf + B_ * L_ * 64;        // B*L*64
  short* UT = SPbf + B_ * L_ * 64;          // B*NC*256*64 = 4.19M shorts
  // total ~23 MB

  kernelA3G<<<256, 256, 0, stream>>>(x, pos, w_val, w_mem1v, w_off, w_key, w_gate,
                                     b_mem1v, b_off, b_key, b_gate, b_val,
                                     m1cT, m1sT, qc, qs, K2bf, gvT, sg, ctxsum);
  scan_all<<<516, 256, 0, stream>>>(m1cT, m1sT, sg, x, ctxsum, ctxbf);
  kernelCDg<<<256, 256, 0, stream>>>(x, ctxbf, w_sk1, b_sk1, w_sk2, b_sk2, gvT,
                                     SPbf, UT);
  kernelE<<<256, 256, 0, stream>>>(UT);
  kernelFGO<<<256, 256, 0, stream>>>(UT, SPbf, K2bf, gvT, sg, m1cT, m1sT, qc, qs,
                                     w_mem1o, b_mem1o, ln_g, ln_b, x, w_out, b_out,
                                     out);
}